// Round 2
// baseline (131.271 us; speedup 1.0000x reference)
//
#include <hip/hip_runtime.h>

// MS_SSA_Conv: spiking self-attention, T=4, C=512, N=196 (14x14), fp32.
// All matmul inputs are spikes {0,1} (~3-4% density) -> sparse masked
// column-sums of W instead of dense GEMM. to_heads is a pure relabeling
// (c = nh*64 + hd), so everything stays in [T,C,N] layout.
//
// R2 changes vs R1 (latency-bound at 1 wave/SIMD, serial 80-iter gather):
//  - 512-thread blocks: 1 thread per output channel, 2 waves/SIMD TLP.
//  - t-interleaved sparse loop: serial chain 80 -> max_t ct (~25) iters,
//    12 independent L2 gathers in flight per iter (ILP latency hiding).
//  - one fewer __syncthreads in ka/kb.

#define TT 4
#define CC 512
#define NN 196
#define BEPS 1e-5f

// ws layout in floats
#define WQT_OFF 0
#define WKT_OFF (512 * 512)
#define WVT_OFF (2 * 512 * 512)
#define WPT_OFF (3 * 512 * 512)
#define KV_OFF  (4 * 512 * 512)            // T*C = 2048 floats
#define SQ_OFF  (4 * 512 * 512 + 2048)     // T*N*16 u32 words = 12544

__global__ __launch_bounds__(256) void k0_prep(
    const float* __restrict__ qw, const float* __restrict__ kw,
    const float* __restrict__ vw, const float* __restrict__ pw,
    float* __restrict__ ws)
{
    __shared__ float tile[64][65];  // +1 pad: conflict-free transpose
    const int b   = blockIdx.x;     // 256 blocks: 4 matrices x 8x8 tiles of 64x64
    const int mat = b >> 6;
    const int t6  = b & 63;
    const int to  = (t6 >> 3) * 64; // o-tile origin
    const int tc  = (t6 & 7) * 64;  // c-tile origin
    const float* W = (mat == 0) ? qw : (mat == 1) ? kw : (mat == 2) ? vw : pw;
    float* Wt = ws + (size_t)mat * (512 * 512);
    const int lr = threadIdx.x >> 6;   // 0..3
    const int lc = threadIdx.x & 63;
#pragma unroll
    for (int i = 0; i < 16; ++i) {
        int r = i * 4 + lr;
        tile[r][lc] = W[(size_t)(to + r) * 512 + (tc + lc)];   // coalesced read
    }
    __syncthreads();
#pragma unroll
    for (int i = 0; i < 16; ++i) {
        int r = i * 4 + lr;   // c-local
        Wt[(size_t)(tc + r) * 512 + (to + lc)] = tile[lc][r];  // coalesced write
    }
    if (b == 0) {
        for (int i = threadIdx.x; i < TT * CC; i += 256) ws[KV_OFF + i] = 0.0f;
    }
}

__device__ __forceinline__ int bn_lif4(const float* acc, float sc, float of, float vth) {
    float v = 0.0f;
    int bits = 0;
#pragma unroll
    for (int t = 0; t < TT; ++t) {
        float y = acc[t] * sc + of;
        v = v + (y - v) * 0.5f;            // v += (y - v)/tau, tau=2
        if (v >= vth) { bits |= (1 << t); v = 0.0f; }
    }
    return bits;
}

// ballot-compact: append set lanes' channel ids to actrow[]
__device__ __forceinline__ void compact_append(int flag, int ch, int lane,
                                               unsigned short* actrow, int* cntp)
{
    unsigned long long m = __ballot(flag);
    int base = 0;
    if (lane == 0 && m) base = atomicAdd(cntp, __popcll(m));
    base = __shfl(base, 0);
    if (flag) actrow[base + __popcll(m & ((1ull << lane) - 1ull))] = (unsigned short)ch;
}

__global__ __launch_bounds__(512) void ka_qkv(
    const float* __restrict__ x, float* __restrict__ ws,
    const float* __restrict__ qg, const float* __restrict__ qb,
    const float* __restrict__ qm, const float* __restrict__ qv,
    const float* __restrict__ kg, const float* __restrict__ kb,
    const float* __restrict__ km, const float* __restrict__ kvv,
    const float* __restrict__ vg, const float* __restrict__ vb,
    const float* __restrict__ vm, const float* __restrict__ vvv)
{
    const int n    = blockIdx.x;      // 0..195
    const int tid  = threadIdx.x;     // owns channel / output tid (0..511)
    const int lane = tid & 63;
    const int wave = tid >> 6;
    __shared__ unsigned short act[TT][CC];
    __shared__ int cnt[TT];
    if (tid < TT) cnt[tid] = 0;

    // --- shortcut LIF on x (local; depends only on this n) ---
    int xf = 0;
    {
        float v = 0.0f;
#pragma unroll
        for (int t = 0; t < TT; ++t) {
            float a = x[(size_t)(t * CC + tid) * NN + n];
            v = v + (a - v) * 0.5f;
            if (v >= 1.0f) { xf |= (1 << t); v = 0.0f; }
        }
    }
    __syncthreads();   // cnt init visible before appends
#pragma unroll
    for (int t = 0; t < TT; ++t)
        compact_append((xf >> t) & 1, tid, lane, act[t], &cnt[t]);
    __syncthreads();

    int ct[TT];
    int mc = 0;
#pragma unroll
    for (int t = 0; t < TT; ++t) { ct[t] = cnt[t]; mc = max(mc, ct[t]); }

    // --- sparse accumulate, t-interleaved for ILP: 12 indep gathers/iter ---
    float aq[TT] = {0,0,0,0}, ak[TT] = {0,0,0,0}, av[TT] = {0,0,0,0};
    const float* Wqt = ws + WQT_OFF;
    const float* Wkt = ws + WKT_OFF;
    const float* Wvt = ws + WVT_OFF;
    for (int i = 0; i < mc; ++i) {
#pragma unroll
        for (int t = 0; t < TT; ++t) {
            if (i < ct[t]) {               // block-uniform branch, no divergence
                const int c = act[t][i];   // LDS broadcast read
                aq[t] += Wqt[(size_t)c * CC + tid];
                ak[t] += Wkt[(size_t)c * CC + tid];
                av[t] += Wvt[(size_t)c * CC + tid];
            }
        }
    }

    // --- BN + LIF (v_th = 1) for this output channel ---
    int sqb, skb, svb;
    {
        float sc = qg[tid] / sqrtf(qv[tid] + BEPS);
        sqb = bn_lif4(aq, sc, qb[tid] - qm[tid] * sc, 1.0f);
        sc = kg[tid] / sqrtf(kvv[tid] + BEPS);
        skb = bn_lif4(ak, sc, kb[tid] - km[tid] * sc, 1.0f);
        sc = vg[tid] / sqrtf(vvv[tid] + BEPS);
        svb = bn_lif4(av, sc, vb[tid] - vm[tid] * sc, 1.0f);
    }

    // --- store sq bitmask; accumulate kvsum[t][c] += sk & sv ---
    unsigned* sqg = (unsigned*)(ws + SQ_OFF);
    float* kvsum = ws + KV_OFF;
#pragma unroll
    for (int t = 0; t < TT; ++t) {
        unsigned long long m = __ballot((sqb >> t) & 1);
        if (lane == 0) {
            sqg[((size_t)t * NN + n) * 16 + wave * 2]     = (unsigned)(m & 0xffffffffULL);
            sqg[((size_t)t * NN + n) * 16 + wave * 2 + 1] = (unsigned)(m >> 32);
        }
        if (((skb >> t) & 1) && ((svb >> t) & 1)) atomicAdd(&kvsum[t * CC + tid], 1.0f);
    }
}

__global__ __launch_bounds__(512) void kb_proj(
    const float* __restrict__ x, const float* __restrict__ ws,
    const float* __restrict__ pbias,
    const float* __restrict__ pg, const float* __restrict__ pb,
    const float* __restrict__ pm, const float* __restrict__ pv,
    float* __restrict__ out)
{
    const int n    = blockIdx.x;
    const int tid  = threadIdx.x;       // 0..511
    const int lane = tid & 63;
    __shared__ unsigned short act[TT][CC];
    __shared__ int cnt[TT];
    if (tid < TT) cnt[tid] = 0;

    const float* kvsum = ws + KV_OFF;
    const unsigned* sqg = (const unsigned*)(ws + SQ_OFF);

    // talking-heads LIF (v_th = 0.5) on kvsum; AND with sq bit for this n
    int f = 0;
    {
        float v = 0.0f;
#pragma unroll
        for (int t = 0; t < TT; ++t) {
            float a = kvsum[t * CC + tid];
            v = v + (a - v) * 0.5f;
            const int s = (v >= 0.5f);
            if (s) v = 0.0f;
            const unsigned w = sqg[((size_t)t * NN + n) * 16 + (tid >> 5)];
            if (s && ((w >> (tid & 31)) & 1)) f |= (1 << t);
        }
    }
    __syncthreads();
#pragma unroll
    for (int t = 0; t < TT; ++t)
        compact_append((f >> t) & 1, tid, lane, act[t], &cnt[t]);
    __syncthreads();

    int ct[TT];
    int mc = 0;
#pragma unroll
    for (int t = 0; t < TT; ++t) { ct[t] = cnt[t]; mc = max(mc, ct[t]); }

    float a[TT] = {0,0,0,0};
    const float* Wpt = ws + WPT_OFF;
    for (int i = 0; i < mc; ++i) {
#pragma unroll
        for (int t = 0; t < TT; ++t) {
            if (i < ct[t]) {
                const int c = act[t][i];
                a[t] += Wpt[(size_t)c * CC + tid];
            }
        }
    }

    // epilogue: (acc + bias)*scale + offset + identity
    {
        const float sc = pg[tid] / sqrtf(pv[tid] + BEPS);
        const float of = pb[tid] - pm[tid] * sc;
        const float bi = pbias[tid];
#pragma unroll
        for (int t = 0; t < TT; ++t) {
            const size_t i0 = (size_t)(t * CC + tid) * NN + n;
            out[i0] = (a[t] + bi) * sc + of + x[i0];
        }
    }
}

extern "C" void kernel_launch(void* const* d_in, const int* in_sizes, int n_in,
                              void* d_out, int out_size, void* d_ws, size_t ws_size,
                              hipStream_t stream) {
    const float* x     = (const float*)d_in[0];
    const float* qw    = (const float*)d_in[1];
    const float* kw    = (const float*)d_in[2];
    const float* vw    = (const float*)d_in[3];
    const float* pw    = (const float*)d_in[4];
    const float* pbias = (const float*)d_in[5];
    const float* qg = (const float*)d_in[6],  *qb = (const float*)d_in[7];
    const float* qm = (const float*)d_in[8],  *qv = (const float*)d_in[9];
    const float* kg = (const float*)d_in[10], *kb = (const float*)d_in[11];
    const float* km = (const float*)d_in[12], *kv = (const float*)d_in[13];
    const float* vg = (const float*)d_in[14], *vb = (const float*)d_in[15];
    const float* vm = (const float*)d_in[16], *vv = (const float*)d_in[17];
    const float* pg = (const float*)d_in[18], *pb = (const float*)d_in[19];
    const float* pm = (const float*)d_in[20], *pv = (const float*)d_in[21];
    float* ws  = (float*)d_ws;
    float* out = (float*)d_out;

    hipLaunchKernelGGL(k0_prep, dim3(256), dim3(256), 0, stream, qw, kw, vw, pw, ws);
    hipLaunchKernelGGL(ka_qkv, dim3(196), dim3(512), 0, stream, x, ws,
                       qg, qb, qm, qv, kg, kb, km, kv, vg, vb, vm, vv);
    hipLaunchKernelGGL(kb_proj, dim3(196), dim3(512), 0, stream, x, ws,
                       pbias, pg, pb, pm, pv, out);
}